// Round 15
// baseline (94.968 us; speedup 1.0000x reference)
//
#include <hip/hip_runtime.h>
#include <hip/hip_bf16.h>

typedef __bf16 bf16_t;
typedef __attribute__((ext_vector_type(8))) __bf16 bf16x8;
typedef __attribute__((ext_vector_type(4))) float f32x4;

#define KDIM 1152
#define NDIM 1152
#define BM 256
#define BN 288
#define NH 36                          /* k-halves of 32 */
#define NTILES 4                       /* 1152/288 */
#define A_PANEL 294912                 /* 128*1152*2 bytes per m-panel */
#define B_SLAB 18432                   /* BN*32*2 bytes per k-32 slab */
#define B_TILE (36 * B_SLAB)           /* per n-tile panel */

__device__ __forceinline__ void gload_lds16(const void* g, void* l) {
    __builtin_amdgcn_global_load_lds(
        (const __attribute__((address_space(1))) void*)g,
        (__attribute__((address_space(3))) void*)l, 16, 0, 0);
}

// X fp32 -> bf16, frag-order (proven): 16B unit u = P*18432 + T*512 + rb*64
// + g*16 + r0 holds rows m=P*128+rb*16+r0, k=T*32+g*8..+7.
__global__ void cvt_x(const float* __restrict__ X, bf16_t* __restrict__ Xb)
{
    const int u = blockIdx.x * 256 + threadIdx.x;
    const int w = u >> 9;
    const int P = w / 36;
    const int T = w - P * 36;
    const int rem = u & 511;
    const int rb = rem >> 6;
    const int g = (rem >> 4) & 3;
    const int r0 = rem & 15;
    const int m = P * 128 + rb * 16 + r0;
    const int k = T * 32 + g * 8;
    const float* src = X + (size_t)m * KDIM + k;
    f32x4 lo = *(const f32x4*)src;
    f32x4 hi = *(const f32x4*)(src + 4);
    bf16x8 v;
    #pragma unroll
    for (int e = 0; e < 4; ++e) { v[e] = (__bf16)lo[e]; v[4 + e] = (__bf16)hi[e]; }
    *(bf16x8*)((char*)Xb + (size_t)u * 16) = v;
}

// Weff panel, fragment-contiguous per n-tile (BN=288, round-9 layout):
//   bf16 idx(n,k) = tile*331776 + (k>>5)*9216 + (nin>>4)*512 + ((k>>3)&3)*128
//                   + (nin&15)*8 + (k&7)
__global__ void build_wb(const float* __restrict__ W,
                         const float* __restrict__ bvec,
                         bf16_t* __restrict__ Bm,
                         float* __restrict__ bias)
{
    const int t = blockIdx.x * blockDim.x + threadIdx.x;
    if (t < NDIM) {
        const int o = t / 9, p = t - o * 9;
        bias[t] = bvec[p * 128 + o];
    }
    const int c = t & 127;
    const int o = (t >> 7) & 127;
    const int p = t >> 14;
    if (p >= 9) return;
    const int r = p / 3, cc = p - r * 3;
    float eff[3][3] = {{0.f,0.f,0.f},{0.f,0.f,0.f},{0.f,0.f,0.f}};
    const float* w = W + (size_t)((p * 128 + o) * 128 + c) * 9;
    #pragma unroll
    for (int i = 0; i < 3; ++i) {
        const int a = (2 + r + i) / 3;
        #pragma unroll
        for (int j = 0; j < 3; ++j) {
            const int bb = (2 + cc + j) / 3;
            eff[a][bb] += w[i * 3 + j];
        }
    }
    const int n = o * 9 + p;
    const int tile = n / BN;
    const int nin = n - tile * BN;
    #pragma unroll
    for (int a = 0; a < 3; ++a)
        #pragma unroll
        for (int bb = 0; bb < 3; ++bb) {
            const int k = c * 9 + a * 3 + bb;
            const size_t idx = (size_t)tile * (B_TILE / 2)
                             + (k >> 5) * (B_SLAB / 2)
                             + (nin >> 4) * 512 + ((k >> 3) & 3) * 128
                             + (nin & 15) * 8 + (k & 7);
            Bm[idx] = (bf16_t)eff[a][bb];
        }
}

// 8-phase GEMM: out[16384,1152] = Xb(bf16 frag-order) * Weff(bf16) + bias.
// BM=256 x BN=288, grid 256 = 1 block/CU (zero tail), 8 waves 4Mx2N
// (wave 64x144, acc 4x9 = 144 VGPR). K = 36 halves of 32, ring of 4 LDS
// slots per operand (A 4x16K + B 4x18K = 136KB). During half h stage half
// h+2 (5 uniform gload_lds/thread); end-of-half vmcnt(5) drains h+1 while
// h+2 flies -> never 0 until tail, ~2 halves of flight per load.
// Each half = 2 phases {ds_read || stage -> BAR -> lgkm0 -> prio1 ->
// 18 MFMA -> prio0 -> BAR}. All frag reads contiguous-1KB (conflict-free).
__launch_bounds__(512, 1)
__global__ void ind_gemm(const bf16_t* __restrict__ Xb,
                         const bf16_t* __restrict__ Bm,
                         const float* __restrict__ bias,
                         float* __restrict__ out)
{
    __shared__ char Ar[4][16384];   // slot: [P-half(2)][rb(8)][1KB frag]
    __shared__ char Br[4][18432];   // slot: builder k-32 slab layout
    __shared__ char Scrap[1024];

    const int tid = threadIdx.x;
    const int lane = tid & 63;
    const int wid = tid >> 6;
    const int wm = wid >> 1;        // 0..3
    const int wn = wid & 1;         // 0..1

    // XCD swizzle: 256 blocks = 32/XCD; consecutive swz share an m-panel
    // across the 4 n-tiles.
    const int bid = blockIdx.x;
    const int swz = (bid & 7) * 32 + (bid >> 3);
    const int mt = swz >> 2;
    const int nt = swz & 3;
    const int m0 = mt * BM;

    const char* apan0 = (const char*)Xb + (size_t)(2 * mt) * A_PANEL;
    const char* apan1 = apan0 + A_PANEL;
    const char* bpan  = (const char*)Bm + (size_t)nt * B_TILE;

    const int fr = (lane >> 4) * 256 + (lane & 15) * 16;
    const int aoff = (wm >> 1) * 8192 + (wm & 1) * 4096;  // + mi*1024 + fr

    f32x4 acc[4][9];
    #pragma unroll
    for (int i = 0; i < 4; ++i)
        #pragma unroll
        for (int j = 0; j < 9; ++j)
            acc[i][j] = (f32x4){0.f, 0.f, 0.f, 0.f};

    bf16x8 af0, af1, af2, af3, bfr[9];

    #define STAGE_A0(H) gload_lds16(apan0 + (size_t)(H) * 8192 + tid * 16,  \
                                    &Ar[(H) & 3][tid * 16])
    #define STAGE_A1(H) gload_lds16(apan1 + (size_t)(H) * 8192 + tid * 16,  \
                                    &Ar[(H) & 3][8192 + tid * 16])
    #define STAGE_B0(H) gload_lds16(bpan + (size_t)(H) * B_SLAB + tid * 16, \
                                    &Br[(H) & 3][tid * 16])
    #define STAGE_B1(H) gload_lds16(bpan + (size_t)(H) * B_SLAB + (tid + 512) * 16, \
                                    &Br[(H) & 3][(tid + 512) * 16])
    #define STAGE_B2(H) do {                                                \
        if (tid < 128)   /* waves 0-1: real remainder */                    \
            gload_lds16(bpan + (size_t)(H) * B_SLAB + (tid + 1024) * 16,    \
                        &Br[(H) & 3][(tid + 1024) * 16]);                   \
        else             /* waves 2-7: dummy, keeps vmcnt uniform */        \
            gload_lds16(bpan + tid * 16, Scrap);                            \
    } while (0)

    #define LDB(S) do {                                                     \
        _Pragma("unroll")                                                   \
        for (int j_ = 0; j_ < 9; ++j_)                                      \
            bfr[j_] = *(const bf16x8*)(&Br[S][(wn * 9 + j_) * 1024 + fr]);  \
    } while (0)

    #define LDA(DST, S, MI)                                                 \
        DST = *(const bf16x8*)(&Ar[S][aoff + (MI) * 1024 + fr])

    #define MM(AF, MI) do {                                                 \
        _Pragma("unroll")                                                   \
        for (int j_ = 0; j_ < 9; ++j_)                                      \
            acc[MI][j_] = __builtin_amdgcn_mfma_f32_16x16x32_bf16(          \
                AF, bfr[j_], acc[MI][j_], 0, 0, 0);                         \
    } while (0)

    #define BAR()   __builtin_amdgcn_s_barrier()
    #define LGKM0() do { asm volatile("s_waitcnt lgkmcnt(0)" ::: "memory"); \
                         __builtin_amdgcn_sched_barrier(0); } while (0)

    // ---- prologue: stage halves 0,1 (10 loads); drain h0, keep h1 flying ----
    STAGE_A0(0); STAGE_A1(0); STAGE_B0(0); STAGE_B1(0); STAGE_B2(0);
    STAGE_A0(1); STAGE_A1(1); STAGE_B0(1); STAGE_B1(1); STAGE_B2(1);
    asm volatile("s_waitcnt vmcnt(5)" ::: "memory");
    __builtin_amdgcn_sched_barrier(0);
    BAR();

    #pragma unroll 1
    for (int h = 0; h < NH; ++h) {
        const int s = h & 3;
        const bool st = (h <= NH - 3);   // stage h+2 exists
        // ---- phase A: bfr + af0/af1, stage 2 of 5 ----
        LDB(s);
        LDA(af0, s, 0); LDA(af1, s, 1);
        if (st) { STAGE_A0(h + 2); STAGE_B0(h + 2); }
        BAR(); LGKM0();
        __builtin_amdgcn_s_setprio(1);
        MM(af0, 0); MM(af1, 1);
        __builtin_amdgcn_s_setprio(0);
        BAR();
        // ---- phase B: af2/af3, stage 3 of 5, end-of-half wait ----
        LDA(af2, s, 2); LDA(af3, s, 3);
        if (st) { STAGE_A1(h + 2); STAGE_B1(h + 2); STAGE_B2(h + 2); }
        BAR(); LGKM0();
        __builtin_amdgcn_s_setprio(1);
        MM(af2, 2); MM(af3, 3);
        __builtin_amdgcn_s_setprio(0);
        if (h <= NH - 3) {
            asm volatile("s_waitcnt vmcnt(5)" ::: "memory"); // h+1 ready
            __builtin_amdgcn_sched_barrier(0);
        } else if (h == NH - 2) {
            asm volatile("s_waitcnt vmcnt(0)" ::: "memory"); // h+1 (last) ready
            __builtin_amdgcn_sched_barrier(0);
        }
        BAR();
    }

    #undef STAGE_A0
    #undef STAGE_A1
    #undef STAGE_B0
    #undef STAGE_B1
    #undef STAGE_B2
    #undef LDB
    #undef LDA
    #undef MM
    #undef BAR
    #undef LGKM0

    // ---- epilogue: C/D col=lane&15, row=(lane>>4)*4+reg ----
    const int orow = (lane >> 4) * 4;
    const int ocol = lane & 15;
    const int gn0 = nt * BN + wn * 144 + ocol;
    #pragma unroll
    for (int ni = 0; ni < 9; ++ni) {
        const float bv = bias[gn0 + ni * 16];
        #pragma unroll
        for (int mi = 0; mi < 4; ++mi) {
            float* po = out + (size_t)(m0 + wm * 64 + mi * 16 + orow) * NDIM
                            + gn0 + ni * 16;
            #pragma unroll
            for (int r = 0; r < 4; ++r)
                po[(size_t)r * NDIM] = acc[mi][ni][r] + bv;
        }
    }
}

extern "C" void kernel_launch(void* const* d_in, const int* in_sizes, int n_in,
                              void* d_out, int out_size, void* d_ws, size_t ws_size,
                              hipStream_t stream)
{
    const float* x  = (const float*)d_in[0];
    const float* W  = (const float*)d_in[1];
    const float* bv = (const float*)d_in[2];
    float* out = (float*)d_out;

    // ws: Xb 37.75 MB | Bm 2.65 MB | bias 4.6 KB
    bf16_t* Xb   = (bf16_t*)d_ws;
    bf16_t* Bm   = (bf16_t*)((char*)d_ws + (size_t)16384 * KDIM * sizeof(bf16_t));
    float*  bias = (float*)((char*)Bm + (size_t)KDIM * NDIM * sizeof(bf16_t));

    cvt_x<<<9216, 256, 0, stream>>>(x, Xb);
    build_wb<<<576, 256, 0, stream>>>(W, bv, Bm, bias);
    ind_gemm<<<256, 512, 0, stream>>>(Xb, Bm, bias, out);
}

// Round 16
// 80.768 us; speedup vs baseline: 1.1758x; 1.1758x over previous
//
#include <hip/hip_runtime.h>
#include <hip/hip_bf16.h>

typedef __bf16 bf16_t;
typedef __attribute__((ext_vector_type(8))) __bf16 bf16x8;
typedef __attribute__((ext_vector_type(4))) float f32x4;

#define KDIM 1152
#define NDIM 1152
#define BM 128
#define BN 192
#define BK 32
#define NIT 36                        /* K-steps of 32 */
#define NTILES 6                      /* 1152/192 */
#define A_STEP 8192                   /* BM*BK*2 bytes per (panel,ktile) */
#define A_PANEL 294912                /* BM*KDIM*2 bytes per m-panel */
#define B_STEP 12288                  /* BN*BK*2 bytes per ktile */
#define B_TILE (36 * B_STEP)          /* per n-tile panel */
#define CVT_BLOCKS 9216               /* 36864 waves, 1 rb-group each */

__device__ __forceinline__ void gload_lds16(const void* g, void* l) {
    __builtin_amdgcn_global_load_lds(
        (const __attribute__((address_space(1))) void*)g,
        (__attribute__((address_space(3))) void*)l, 16, 0, 0);
}

// Fused prep: blocks [0,9216) convert X fp32->bf16 into frag-order Xb
// (coalesced read via wave-local LDS transpose, coalesced 1KB/wave write);
// blocks [9216,9792) fold W -> Weff panels + bias.
// Xb frag-order (proven): unit = P*18432 + T*512 + rb*64 + g*16 + r0
//   holds row m=P*128+rb*16+r0, k=T*32+g*8..+7.
// Weff (proven): bf16 idx(n,k) = tile*221184 + (k>>5)*6144 + (nin>>4)*512
//   + ((k>>3)&3)*128 + (nin&15)*8 + (k&7)    (tile=n/192, nin=n%192)
__global__ void prep(const float* __restrict__ X, bf16_t* __restrict__ Xb,
                     const float* __restrict__ W, const float* __restrict__ bvec,
                     bf16_t* __restrict__ Bm, float* __restrict__ bias)
{
    __shared__ char L[4096];
    const int bid = blockIdx.x;
    const int tid = threadIdx.x;
    if (bid < CVT_BLOCKS) {
        const int wv = (bid << 2) + (tid >> 6);      // rb-group id, 0..36863
        const int l = tid & 63;
        const int P = wv / 288;
        const int rem = wv - P * 288;
        const int T = rem >> 3;
        const int rb = rem & 7;
        // read: lane -> (row r0=l>>2, k-chunk g=l&3): 128B contiguous per 4 lanes
        const int row = P * 128 + rb * 16 + (l >> 2);
        const int k = T * 32 + (l & 3) * 8;
        const float* src = X + (size_t)row * KDIM + k;
        f32x4 lo = *(const f32x4*)src;
        f32x4 hi = *(const f32x4*)(src + 4);
        bf16x8 v;
        #pragma unroll
        for (int e = 0; e < 4; ++e) { v[e] = (__bf16)lo[e]; v[4 + e] = (__bf16)hi[e]; }
        // transpose through wave-local 1KB: unit u = g*16 + r0
        char* wl = L + (tid >> 6) * 1024;
        *(bf16x8*)(wl + ((l & 3) * 16 + (l >> 2)) * 16) = v;
        __builtin_amdgcn_s_barrier();
        bf16x8 o = *(const bf16x8*)(wl + l * 16);
        *(bf16x8*)((char*)Xb + ((size_t)wv * 64 + l) * 16) = o;   // 1KB/wave coalesced
        return;
    }
    const int t = (bid - CVT_BLOCKS) * 256 + tid;
    if (t < NDIM) {
        const int o = t / 9, p = t - o * 9;
        bias[t] = bvec[p * 128 + o];
    }
    const int c = t & 127;
    const int o = (t >> 7) & 127;
    const int p = t >> 14;
    if (p >= 9) return;
    const int r = p / 3, cc = p - r * 3;
    float eff[3][3] = {{0.f,0.f,0.f},{0.f,0.f,0.f},{0.f,0.f,0.f}};
    const float* w = W + (size_t)((p * 128 + o) * 128 + c) * 9;
    #pragma unroll
    for (int i = 0; i < 3; ++i) {
        const int a = (2 + r + i) / 3;
        #pragma unroll
        for (int j = 0; j < 3; ++j) {
            const int bb = (2 + cc + j) / 3;
            eff[a][bb] += w[i * 3 + j];
        }
    }
    const int n = o * 9 + p;
    const int tile = n / BN;
    const int nin = n - tile * BN;
    #pragma unroll
    for (int a = 0; a < 3; ++a)
        #pragma unroll
        for (int bb = 0; bb < 3; ++bb) {
            const int k = c * 9 + a * 3 + bb;
            const size_t idx = (size_t)tile * (B_TILE / 2)
                             + (k >> 5) * (B_STEP / 2)
                             + (nin >> 4) * 512 + ((k >> 3) & 3) * 128
                             + (nin & 15) * 8 + (k & 7);
            Bm[idx] = (bf16_t)eff[a][bb];
        }
}

// out[16384,1152] = Xb(bf16 frag-order) * Weff(bf16) + bias.
// Round-13 structure + A global->reg with DEPTH-2 flight:
// iter t: {RDB(cur): 6 ds_read + lgkm0 + barrier} -> GLDB(t+2,cur)[+3]
//   -> MFMA24(af_cur) -> LOADA(t+2 -> af_cur, WAR-ordered after MFMA)[+4]
//   -> vmcnt(7) (drains B(t+1)+A(t+1); keeps t+2 in flight) -> barrier.
// A loads get >=1 full iter (~1200cy) of flight; LDS traffic 36KB/block-iter
// (B stage 12K + B read 24K) = ~98 B/cy at 3 blocks/CU — under the pipe cap.
__launch_bounds__(256, 3)
__global__ void ind_gemm(const bf16_t* __restrict__ Xb,
                         const bf16_t* __restrict__ Bm,
                         const float* __restrict__ bias,
                         float* __restrict__ out)
{
    __shared__ char Bs[2][B_STEP];

    const int tid = threadIdx.x;
    const int lane = tid & 63;
    const int wid = tid >> 6;
    const int wm = wid >> 1;        // 0..1
    const int wn = wid & 1;         // 0..1

    // XCD swizzle: 768 blocks = 96/XCD; consecutive swz share an m-panel
    // (147KB bf16, L2-resident) across the 6 n-tiles.
    const int bid = blockIdx.x;
    const int swz = (bid & 7) * 96 + (bid >> 3);
    const int mt = swz / NTILES;
    const int nt = swz - mt * NTILES;
    const int m0 = mt * BM;

    const int fr = (lane >> 4) * 256 + (lane & 15) * 16;
    const char* apl = (const char*)Xb + (size_t)mt * A_PANEL + wm * 4096 + fr;
    const char* bpanel = (const char*)Bm + (size_t)nt * B_TILE;

    f32x4 acc[4][6];
    #pragma unroll
    for (int i = 0; i < 4; ++i)
        #pragma unroll
        for (int j = 0; j < 6; ++j)
            acc[i][j] = (f32x4){0.f, 0.f, 0.f, 0.f};

    f32x4 afA[4], afB[4];           // A frag sets (raw 16B), ping-pong by parity
    bf16x8 bfr[6];

    #define LOADA(T, AF) do {                                               \
        const char* p_ = apl + (size_t)(T) * A_STEP;                        \
        asm volatile("global_load_dwordx4 %0, %4, off\n\t"                  \
                     "global_load_dwordx4 %1, %4, off offset:1024\n\t"      \
                     "global_load_dwordx4 %2, %4, off offset:2048\n\t"      \
                     "global_load_dwordx4 %3, %4, off offset:3072"          \
                     : "=&v"(AF[0]), "=&v"(AF[1]), "=&v"(AF[2]), "=&v"(AF[3]) \
                     : "v"(p_) : "memory");                                 \
    } while (0)

    #define GLDB(T, BUF) do {                                               \
        const char* s_ = bpanel + (size_t)(T) * B_STEP;                     \
        _Pragma("unroll")                                                   \
        for (int r_ = 0; r_ < 3; ++r_) {                                    \
            const int u_ = (tid + r_ * 256) * 16;                           \
            gload_lds16(s_ + u_, &Bs[BUF][u_]);                             \
        } } while (0)

    #define RDB(CUR) do {                                                   \
        _Pragma("unroll")                                                   \
        for (int j_ = 0; j_ < 6; ++j_)                                      \
            bfr[j_] = *(const bf16x8*)(&Bs[CUR][(wn * 6 + j_) * 1024 + fr]); \
        asm volatile("s_waitcnt lgkmcnt(0)" ::: "memory");                  \
        __builtin_amdgcn_sched_barrier(0);                                  \
        __builtin_amdgcn_s_barrier();                                       \
    } while (0)

    #define MFMA24(AF) do {                                                 \
        __builtin_amdgcn_s_setprio(1);                                      \
        _Pragma("unroll")                                                   \
        for (int mi = 0; mi < 4; ++mi) {                                    \
            const bf16x8 a_ = __builtin_bit_cast(bf16x8, AF[mi]);           \
            _Pragma("unroll")                                               \
            for (int j_ = 0; j_ < 6; ++j_)                                  \
                acc[mi][j_] = __builtin_amdgcn_mfma_f32_16x16x32_bf16(      \
                    a_, bfr[j_], acc[mi][j_], 0, 0, 0);                     \
        }                                                                   \
        __builtin_amdgcn_s_setprio(0);                                      \
    } while (0)

    #define WAITV(N) do {                                                   \
        asm volatile("s_waitcnt vmcnt(" #N ")" ::: "memory");               \
        __builtin_amdgcn_sched_barrier(0);                                  \
    } while (0)

    // ---- prologue: A(0)[4] B(0)[3] A(1)[4] B(1)[3] in flight ----
    LOADA(0, afA);
    GLDB(0, 0);
    LOADA(1, afB);
    GLDB(1, 1);
    WAITV(7);                        // A(0)+B(0) done; A(1)+B(1) fly
    __builtin_amdgcn_s_barrier();

    // steady state: 17 double-iters (t = 0..33)
    #pragma unroll 1
    for (int t2 = 0; t2 < 17; ++t2) {
        const int t = 2 * t2;
        // ---- even iter t (cur=0, compute afA) ----
        RDB(0);                      // read B(t); barrier frees Bs[0]
        GLDB(t + 2, 0);              // +3
        MFMA24(afA);                 // consumes afA = A(t)
        LOADA(t + 2, afA);           // +4 (WAR after MFMA: reuses freed set)
        WAITV(7);                    // drains B(t+1)+A(t+1); t+2 stays in flight
        __builtin_amdgcn_s_barrier();
        // ---- odd iter t+1 (cur=1, compute afB) ----
        RDB(1);
        GLDB(t + 3, 1);
        MFMA24(afB);
        LOADA(t + 3, afB);
        WAITV(7);
        __builtin_amdgcn_s_barrier();
    }
    // ---- t = 34 (cur=0, afA): no staging; drain everything ----
    RDB(0);
    MFMA24(afA);
    WAITV(0);                        // B(35)+A(35) complete
    __builtin_amdgcn_s_barrier();
    // ---- t = 35 (cur=1, afB): compute-only ----
    RDB(1);
    MFMA24(afB);

    #undef LOADA
    #undef GLDB
    #undef RDB
    #undef MFMA24
    #undef WAITV

    // ---- epilogue: C/D col=lane&15, row=(lane>>4)*4+reg ----
    const int orow = (lane >> 4) * 4;
    const int ocol = lane & 15;
    const int gn0 = nt * BN + wn * 96 + ocol;
    #pragma unroll
    for (int ni = 0; ni < 6; ++ni) {
        const float bv = bias[gn0 + ni * 16];
        #pragma unroll
        for (int mi = 0; mi < 4; ++mi) {
            float* po = out + (size_t)(m0 + wm * 64 + mi * 16 + orow) * NDIM
                            + gn0 + ni * 16;
            #pragma unroll
            for (int r = 0; r < 4; ++r)
                po[(size_t)r * NDIM] = acc[mi][ni][r] + bv;
        }
    }
}

extern "C" void kernel_launch(void* const* d_in, const int* in_sizes, int n_in,
                              void* d_out, int out_size, void* d_ws, size_t ws_size,
                              hipStream_t stream)
{
    const float* x  = (const float*)d_in[0];
    const float* W  = (const float*)d_in[1];
    const float* bv = (const float*)d_in[2];
    float* out = (float*)d_out;

    // ws: Xb 37.75 MB | Bm 2.65 MB | bias 4.6 KB
    bf16_t* Xb   = (bf16_t*)d_ws;
    bf16_t* Bm   = (bf16_t*)((char*)d_ws + (size_t)16384 * KDIM * sizeof(bf16_t));
    float*  bias = (float*)((char*)Bm + (size_t)KDIM * NDIM * sizeof(bf16_t));

    prep<<<CVT_BLOCKS + 576, 256, 0, stream>>>(x, Xb, W, bv, Bm, bias);
    ind_gemm<<<768, 256, 0, stream>>>(Xb, Bm, bias, out);
}

// Round 17
// 79.979 us; speedup vs baseline: 1.1874x; 1.0099x over previous
//
#include <hip/hip_runtime.h>
#include <hip/hip_bf16.h>

typedef __bf16 bf16_t;
typedef __attribute__((ext_vector_type(8))) __bf16 bf16x8;
typedef __attribute__((ext_vector_type(4))) float f32x4;

#define KDIM 1152
#define NDIM 1152
#define BM 128
#define BN 288
#define BK 32
#define NIT 36                        /* K-steps of 32 */
#define NTILES 4                      /* 1152/288 */
#define A_STEP 8192                   /* BM*BK*2 bytes per (panel,ktile) */
#define A_PANEL 294912                /* BM*KDIM*2 bytes per m-panel */
#define B_STEP 18432                  /* BN*BK*2 bytes per ktile */
#define B_TILE (36 * B_STEP)          /* 663552 B per n-tile panel */
#define CVT_BLOCKS 9216

__device__ __forceinline__ void gload_lds16(const void* g, void* l) {
    __builtin_amdgcn_global_load_lds(
        (const __attribute__((address_space(1))) void*)g,
        (__attribute__((address_space(3))) void*)l, 16, 0, 0);
}

// Fused prep (round-16, proven): blocks [0,9216) cvt X fp32->bf16 frag-order;
// blocks [9216,9792) fold W -> Weff (BN=288 layout) + bias.
// Xb: unit = P*18432 + T*512 + rb*64 + g*16 + r0 -> row P*128+rb*16+r0, k T*32+g*8.
// Weff: idx(n,k) = tile*331776 + (k>>5)*9216 + (nin>>4)*512 + ((k>>3)&3)*128
//       + (nin&15)*8 + (k&7)   (tile = n/288, nin = n%288)
__global__ void prep(const float* __restrict__ X, bf16_t* __restrict__ Xb,
                     const float* __restrict__ W, const float* __restrict__ bvec,
                     bf16_t* __restrict__ Bm, float* __restrict__ bias)
{
    __shared__ char L[4096];
    const int bid = blockIdx.x;
    const int tid = threadIdx.x;
    if (bid < CVT_BLOCKS) {
        const int wv = (bid << 2) + (tid >> 6);
        const int l = tid & 63;
        const int P = wv / 288;
        const int rem = wv - P * 288;
        const int T = rem >> 3;
        const int rb = rem & 7;
        const int row = P * 128 + rb * 16 + (l >> 2);
        const int k = T * 32 + (l & 3) * 8;
        const float* src = X + (size_t)row * KDIM + k;
        f32x4 lo = *(const f32x4*)src;
        f32x4 hi = *(const f32x4*)(src + 4);
        bf16x8 v;
        #pragma unroll
        for (int e = 0; e < 4; ++e) { v[e] = (__bf16)lo[e]; v[4 + e] = (__bf16)hi[e]; }
        char* wl = L + (tid >> 6) * 1024;
        *(bf16x8*)(wl + ((l & 3) * 16 + (l >> 2)) * 16) = v;
        __builtin_amdgcn_s_barrier();
        bf16x8 o = *(const bf16x8*)(wl + l * 16);
        *(bf16x8*)((char*)Xb + ((size_t)wv * 64 + l) * 16) = o;
        return;
    }
    const int t = (bid - CVT_BLOCKS) * 256 + tid;
    if (t < NDIM) {
        const int o = t / 9, p = t - o * 9;
        bias[t] = bvec[p * 128 + o];
    }
    const int c = t & 127;
    const int o = (t >> 7) & 127;
    const int p = t >> 14;
    if (p >= 9) return;
    const int r = p / 3, cc = p - r * 3;
    float eff[3][3] = {{0.f,0.f,0.f},{0.f,0.f,0.f},{0.f,0.f,0.f}};
    const float* w = W + (size_t)((p * 128 + o) * 128 + c) * 9;
    #pragma unroll
    for (int i = 0; i < 3; ++i) {
        const int a = (2 + r + i) / 3;
        #pragma unroll
        for (int j = 0; j < 3; ++j) {
            const int bb = (2 + cc + j) / 3;
            eff[a][bb] += w[i * 3 + j];
        }
    }
    const int n = o * 9 + p;
    const int tile = n / BN;
    const int nin = n - tile * BN;
    #pragma unroll
    for (int a = 0; a < 3; ++a)
        #pragma unroll
        for (int bb = 0; bb < 3; ++bb) {
            const int k = c * 9 + a * 3 + bb;
            const size_t idx = (size_t)tile * (B_TILE / 2)
                             + (k >> 5) * (B_STEP / 2)
                             + (nin >> 4) * 512 + ((k >> 3) & 3) * 128
                             + (nin & 15) * 8 + (k & 7);
            Bm[idx] = (bf16_t)eff[a][bb];
        }
}

// out[16384,1152] = Xb(bf16 frag-order) * Weff(bf16) + bias.
// Round-13 sync skeleton, BIGGER TILE for L2 arithmetic intensity:
// BM=128 x BN=288, grid 512 = exactly 2 blocks/CU. 4 waves (2m x 2n),
// wave 64x144, acc 4x9 = 144 VGPR. Both operands dbuf-LDS via linear
// gload_lds (A 2/thr + B 5/thr, 5th dummy for tid>=128 -> vmcnt uniform).
// Ledger: enter with 7 in flight; stage t+2 (+7); vmcnt(7) drains t+1;
// 0 only at the tail. Per CU-iter: L2 52KB (929cy) < MFMA 1160cy -> MFMA-bound.
__launch_bounds__(256, 2)
__global__ void ind_gemm(const bf16_t* __restrict__ Xb,
                         const bf16_t* __restrict__ Bm,
                         const float* __restrict__ bias,
                         float* __restrict__ out)
{
    __shared__ char As[2][A_STEP];
    __shared__ char Bs[2][B_STEP];
    __shared__ char Scrap[1024];

    const int tid = threadIdx.x;
    const int lane = tid & 63;
    const int wid = tid >> 6;
    const int wm = wid >> 1;        // 0..1
    const int wn = wid & 1;         // 0..1

    // XCD swizzle: 512 blocks = 64/XCD; consecutive swz share an m-panel
    // (147KB bf16, L2-resident) across the 4 n-tiles.
    const int bid = blockIdx.x;
    const int swz = (bid & 7) * 64 + (bid >> 3);
    const int mt = swz >> 2;
    const int nt = swz & 3;
    const int m0 = mt * BM;

    const int fr = (lane >> 4) * 256 + (lane & 15) * 16;
    const char* apanel = (const char*)Xb + (size_t)mt * A_PANEL;
    const char* bpanel = (const char*)Bm + (size_t)nt * B_TILE;

    f32x4 acc[4][9];
    #pragma unroll
    for (int i = 0; i < 4; ++i)
        #pragma unroll
        for (int j = 0; j < 9; ++j)
            acc[i][j] = (f32x4){0.f, 0.f, 0.f, 0.f};

    bf16x8 af[4], bfr[9];

    #define GLD(T, BUF) do {                                                \
        const char* sa_ = apanel + (size_t)(T) * A_STEP;                    \
        gload_lds16(sa_ + tid * 16,        &As[BUF][tid * 16]);             \
        gload_lds16(sa_ + 4096 + tid * 16, &As[BUF][4096 + tid * 16]);      \
        const char* sb_ = bpanel + (size_t)(T) * B_STEP;                    \
        _Pragma("unroll")                                                   \
        for (int r_ = 0; r_ < 4; ++r_) {                                    \
            const int u_ = (tid + r_ * 256) * 16;                           \
            gload_lds16(sb_ + u_, &Bs[BUF][u_]);                            \
        }                                                                   \
        if (tid < 128) gload_lds16(sb_ + (1024 + tid) * 16,                 \
                                   &Bs[BUF][(1024 + tid) * 16]);            \
        else           gload_lds16(bpanel + tid * 16, Scrap);               \
    } while (0)

    #define RD(CUR) do {                                                    \
        _Pragma("unroll")                                                   \
        for (int mi_ = 0; mi_ < 4; ++mi_)                                   \
            af[mi_] = *(const bf16x8*)(&As[CUR][(wm * 4 + mi_) * 1024 + fr]); \
        _Pragma("unroll")                                                   \
        for (int j_ = 0; j_ < 9; ++j_)                                      \
            bfr[j_] = *(const bf16x8*)(&Bs[CUR][(wn * 9 + j_) * 1024 + fr]); \
        asm volatile("s_waitcnt lgkmcnt(0)" ::: "memory");                  \
        __builtin_amdgcn_sched_barrier(0);                                  \
        __builtin_amdgcn_s_barrier();                                       \
    } while (0)

    #define MFMA36() do {                                                   \
        __builtin_amdgcn_s_setprio(1);                                      \
        _Pragma("unroll")                                                   \
        for (int mi_ = 0; mi_ < 4; ++mi_)                                   \
            _Pragma("unroll")                                               \
            for (int j_ = 0; j_ < 9; ++j_)                                  \
                acc[mi_][j_] = __builtin_amdgcn_mfma_f32_16x16x32_bf16(     \
                    af[mi_], bfr[j_], acc[mi_][j_], 0, 0, 0);               \
        __builtin_amdgcn_s_setprio(0);                                      \
    } while (0)

    #define WAITV(N) do {                                                   \
        asm volatile("s_waitcnt vmcnt(" #N ")" ::: "memory");               \
        __builtin_amdgcn_sched_barrier(0);                                  \
    } while (0)

    // ---- prologue: t0[7] + t1[7] in flight; drain t0, keep t1 flying ----
    GLD(0, 0);
    GLD(1, 1);
    WAITV(7);
    __builtin_amdgcn_s_barrier();

    // steady state: 17 double-iters (t = 0..33)
    #pragma unroll 1
    for (int t2 = 0; t2 < 17; ++t2) {
        const int t = 2 * t2;
        // ---- even iter t (cur=0) ----
        RD(0);                       // 13 ds_read, lgkm0, barrier (frees buf0)
        GLD(t + 2, 0);               // +7 -> 14 in flight
        MFMA36();
        WAITV(7);                    // drains t+1; t+2 stays in flight
        __builtin_amdgcn_s_barrier();
        // ---- odd iter t+1 (cur=1) ----
        RD(1);
        GLD(t + 3, 1);
        MFMA36();
        WAITV(7);
        __builtin_amdgcn_s_barrier();
    }
    // ---- t = 34 (cur=0): no staging; drain all ----
    RD(0);
    MFMA36();
    WAITV(0);
    __builtin_amdgcn_s_barrier();
    // ---- t = 35 (cur=1): compute-only ----
    RD(1);
    MFMA36();

    #undef GLD
    #undef RD
    #undef MFMA36
    #undef WAITV

    // ---- epilogue: C/D col=lane&15, row=(lane>>4)*4+reg ----
    const int orow = (lane >> 4) * 4;
    const int ocol = lane & 15;
    const int gn0 = nt * BN + wn * 144 + ocol;
    #pragma unroll
    for (int ni = 0; ni < 9; ++ni) {
        const float bv = bias[gn0 + ni * 16];
        #pragma unroll
        for (int mi = 0; mi < 4; ++mi) {
            float* po = out + (size_t)(m0 + wm * 64 + mi * 16 + orow) * NDIM
                            + gn0 + ni * 16;
            #pragma unroll
            for (int r = 0; r < 4; ++r)
                po[(size_t)r * NDIM] = acc[mi][ni][r] + bv;
        }
    }
}

extern "C" void kernel_launch(void* const* d_in, const int* in_sizes, int n_in,
                              void* d_out, int out_size, void* d_ws, size_t ws_size,
                              hipStream_t stream)
{
    const float* x  = (const float*)d_in[0];
    const float* W  = (const float*)d_in[1];
    const float* bv = (const float*)d_in[2];
    float* out = (float*)d_out;

    // ws: Xb 37.75 MB | Bm 2.65 MB | bias 4.6 KB
    bf16_t* Xb   = (bf16_t*)d_ws;
    bf16_t* Bm   = (bf16_t*)((char*)d_ws + (size_t)16384 * KDIM * sizeof(bf16_t));
    float*  bias = (float*)((char*)Bm + (size_t)KDIM * NDIM * sizeof(bf16_t));

    prep<<<CVT_BLOCKS + 576, 256, 0, stream>>>(x, Xb, W, bv, Bm, bias);
    ind_gemm<<<512, 256, 0, stream>>>(Xb, Bm, bias, out);
}